// Round 1
// baseline (526.776 us; speedup 1.0000x reference)
//
#include <hip/hip_runtime.h>
#include <hip/hip_bf16.h>

#define BB 2
#define SS 2048
#define DM 2048
#define NH 16
#define NKV 4
#define DH 128
#define QS 3072   // packed qkv row stride: 2048 q | 512 k | 512 v

typedef __hip_bfloat16 bf16;
typedef short short8 __attribute__((ext_vector_type(8)));
typedef float floatx4 __attribute__((ext_vector_type(4)));

__device__ __forceinline__ bf16 f2b(float v) { return __float2bfloat16(v); }
__device__ __forceinline__ short f2bs(float v) {
    bf16 t = __float2bfloat16(v);
    return __builtin_bit_cast(short, t);
}
__device__ __forceinline__ void store_c(bf16* p, float v) { *p = __float2bfloat16(v); }
__device__ __forceinline__ void store_c(float* p, float v) { *p = v; }

// ---------------- x fp32 -> bf16 (vectorized)
__global__ __launch_bounds__(256) void convert_x(const float4* __restrict__ x,
                                                 bf16* __restrict__ xb, int n4) {
    int i = blockIdx.x * blockDim.x + threadIdx.x;
    if (i >= n4) return;
    float4 v = x[i];
    bf16* p = xb + (size_t)i * 4;
    p[0] = f2b(v.x); p[1] = f2b(v.y); p[2] = f2b(v.z); p[3] = f2b(v.w);
}

// ---------------- weight fp32 [Kd][N] -> bf16 transposed [N][Kd]
__global__ __launch_bounds__(256) void convert_wT(const float* __restrict__ w,
                                                  bf16* __restrict__ outT,
                                                  int N, int Kd) {
    const int n0 = blockIdx.x * 64, k0 = blockIdx.y * 64;
    __shared__ float tile[64][65];
    const int tid = threadIdx.x;
    for (int i = tid; i < 4096; i += 256) {
        int r = i >> 6, c = i & 63;  // r: k-local, c: n-local
        tile[r][c] = w[(size_t)(k0 + r) * N + n0 + c];
    }
    __syncthreads();
    for (int i = tid; i < 4096; i += 256) {
        int r = i >> 6, c = i & 63;  // r: n-local, c: k-local
        outT[(size_t)(n0 + r) * Kd + k0 + c] = f2b(tile[c][r]);
    }
}

// ---------------- MFMA GEMM: C[M,N] = A[M,K] @ BT[N,K]^T, bf16 in, fp32 acc
// 128x128 tile, BK=32, 4 waves (2x2 of 64x64), 16x16x32 bf16 MFMA.
template <typename TC>
__global__ __launch_bounds__(256) void mfma_gemm(const bf16* __restrict__ A,
                                                 const bf16* __restrict__ BT,
                                                 TC* __restrict__ C,
                                                 int M, int N, int K) {
    __shared__ short As[128 * 32];
    __shared__ short Bs[128 * 32];
    const int tid = threadIdx.x;
    const int w = tid >> 6, lane = tid & 63;
    const int col16 = lane & 15, quad = lane >> 4;
    const int row0 = blockIdx.y * 128, col0 = blockIdx.x * 128;
    const int wr0 = (w >> 1) * 64, wc0 = (w & 1) * 64;

    floatx4 acc[4][4];
    #pragma unroll
    for (int mi = 0; mi < 4; mi++)
        #pragma unroll
        for (int ni = 0; ni < 4; ni++) acc[mi][ni] = (floatx4){0.f, 0.f, 0.f, 0.f};

    for (int k0 = 0; k0 < K; k0 += 32) {
        __syncthreads();
        #pragma unroll
        for (int it = 0; it < 2; it++) {
            int c = w * 128 + it * 64 + lane;
            int r = c >> 2, seg = c & 3;
            const bf16* g = A + (size_t)(row0 + r) * K + k0 + seg * 8;
            __builtin_amdgcn_global_load_lds(
                (const __attribute__((address_space(1))) unsigned int*)g,
                (__attribute__((address_space(3))) unsigned int*)&As[(w * 128 + it * 64) * 8],
                16, 0, 0);
        }
        #pragma unroll
        for (int it = 0; it < 2; it++) {
            int c = w * 128 + it * 64 + lane;
            int r = c >> 2, seg = c & 3;
            const bf16* g = BT + (size_t)(col0 + r) * K + k0 + seg * 8;
            __builtin_amdgcn_global_load_lds(
                (const __attribute__((address_space(1))) unsigned int*)g,
                (__attribute__((address_space(3))) unsigned int*)&Bs[(w * 128 + it * 64) * 8],
                16, 0, 0);
        }
        __syncthreads();

        short8 af[4], bfr[4];
        #pragma unroll
        for (int mi = 0; mi < 4; mi++)
            af[mi] = *(const short8*)&As[(wr0 + mi * 16 + col16) * 32 + quad * 8];
        #pragma unroll
        for (int ni = 0; ni < 4; ni++)
            bfr[ni] = *(const short8*)&Bs[(wc0 + ni * 16 + col16) * 32 + quad * 8];
        #pragma unroll
        for (int mi = 0; mi < 4; mi++)
            #pragma unroll
            for (int ni = 0; ni < 4; ni++)
                acc[mi][ni] = __builtin_amdgcn_mfma_f32_16x16x32_bf16(af[mi], bfr[ni], acc[mi][ni], 0, 0, 0);
    }
    #pragma unroll
    for (int mi = 0; mi < 4; mi++)
        #pragma unroll
        for (int ni = 0; ni < 4; ni++)
            #pragma unroll
            for (int r = 0; r < 4; r++)
                store_c(&C[(size_t)(row0 + wr0 + mi * 16 + quad * 4 + r) * N +
                           col0 + wc0 + ni * 16 + col16],
                        acc[mi][ni][r]);
}

// ---------------- RoPE (interleaved pairs) on packed qkv
__global__ void rope_kernel(bf16* __restrict__ base, const float* __restrict__ cs,
                            const float* __restrict__ sn, int n_heads, int total) {
    int idx = blockIdx.x * blockDim.x + threadIdx.x;
    if (idx >= total) return;
    int i = idx & 63;
    int h = (idx >> 6) % n_heads;
    size_t bs = (size_t)idx / (64 * n_heads);
    int s = (int)(bs % SS);
    float c = cs[s * 64 + i];
    float si = sn[s * 64 + i];
    bf16* p = base + bs * QS + h * DH + 2 * i;
    float xr = __bfloat162float(p[0]), xi = __bfloat162float(p[1]);
    p[0] = f2b(xr * c - xi * si);
    p[1] = f2b(xr * si + xi * c);
}

// ---------------- V transpose: qkv packed v -> vt[b][kvh][d][s]
__global__ __launch_bounds__(256) void transpose_v(const bf16* __restrict__ qkv,
                                                   bf16* __restrict__ vt) {
    const int s0 = blockIdx.x * 64, d0 = blockIdx.y * 64;
    const int b = blockIdx.z >> 2, kvh = blockIdx.z & 3;
    __shared__ bf16 tile[64][65];
    const int tid = threadIdx.x;
    for (int i = tid; i < 4096; i += 256) {
        int r = i >> 6, c = i & 63;
        tile[r][c] = qkv[(size_t)(b * SS + s0 + r) * QS + 2560 + kvh * DH + d0 + c];
    }
    __syncthreads();
    for (int i = tid; i < 4096; i += 256) {
        int r = i >> 6, c = i & 63;
        vt[((size_t)(b * NKV + kvh) * DH + d0 + r) * SS + s0 + c] = tile[c][r];
    }
}

// ---------------- Flash attention (causal, GQA), bf16 MFMA 16x16x32
// De-staged version: K and V MFMA fragments are 16B-contiguous slices of the
// global qkv / vt rows; K+V working set per (b,kvh) is 1 MB (L2-resident), so
// LDS staging + its 2 barriers/tile were pure overhead (Common-mistake #7).
// No __syncthreads remain: Ps is per-wave (same-wave write->read, compiler
// orders via lgkmcnt). Waves drift independently -> L2 latency mutually hidden;
// setprio(1) around MFMA clusters (m191 regime: independent waves).
// Causal load-balance pairing: block bx processes Q-tile bx, then Q-tile
// (SS/64-1)-bx  =>  every block does exactly (SS/64)+1 = 33 K-tile iters.
#define PPAD 72

__global__ __launch_bounds__(256) void flash_attn(const bf16* __restrict__ qkv,
                                                  const bf16* __restrict__ vt,
                                                  bf16* __restrict__ ao) {
    const int bx = blockIdx.x, h = blockIdx.y, b = blockIdx.z;
    const int kvh = h >> 2;
    __shared__ short Ps[4 * 16 * PPAD];
    const int tid = threadIdx.x;
    const int w = tid >> 6, lane = tid & 63;
    const int col = lane & 15, quad = lane >> 4;
    const float scale = 0.08838834764831845f;

    // K fragment base: row (k0 + n*16 + col) of K, byte offset kc*32 + quad*8 shorts
    const bf16* kb = qkv + ((size_t)b * SS + col) * QS + 2048 + kvh * DH + quad * 8;
    // V fragment base: vt row (dt*16 + col), s-offset k0 + quad*8 (+32)
    const bf16* vb = vt + ((size_t)(b * NKV + kvh) * DH + col) * SS + quad * 8;

    for (int phase = 0; phase < 2; phase++) {
        const int qt = phase == 0 ? bx : (SS / 64 - 1 - bx);
        const int q0 = qt * 64;

        short8 aq[4];
        const bf16* qbase = qkv + (size_t)(b * SS + q0 + w * 16 + col) * QS + h * DH;
        #pragma unroll
        for (int kc = 0; kc < 4; kc++)
            aq[kc] = *(const short8*)(qbase + kc * 32 + quad * 8);

        floatx4 o[8];
        #pragma unroll
        for (int dt = 0; dt < 8; dt++) o[dt] = (floatx4){0.f, 0.f, 0.f, 0.f};
        float mrow[4] = {-3e38f, -3e38f, -3e38f, -3e38f};
        float lrow[4] = {0.f, 0.f, 0.f, 0.f};

        for (int kt = 0; kt <= qt; kt++) {
            const int k0 = kt * 64;
            const bf16* kt_base = kb + (size_t)k0 * QS;
            const bf16* vt_base = vb + k0;

            floatx4 s[4];
            __builtin_amdgcn_s_setprio(1);
            #pragma unroll
            for (int n = 0; n < 4; n++) {
                s[n] = (floatx4){0.f, 0.f, 0.f, 0.f};
                #pragma unroll
                for (int kc = 0; kc < 4; kc++) {
                    short8 bk = *(const short8*)(kt_base + (size_t)(n * 16) * QS + kc * 32);
                    s[n] = __builtin_amdgcn_mfma_f32_16x16x32_bf16(aq[kc], bk, s[n], 0, 0, 0);
                }
            }
            __builtin_amdgcn_s_setprio(0);

            #pragma unroll
            for (int n = 0; n < 4; n++)
                #pragma unroll
                for (int r = 0; r < 4; r++) {
                    float v = s[n][r] * scale;
                    if (kt == qt && (k0 + n * 16 + col) > (q0 + w * 16 + quad * 4 + r)) v = -3e38f;
                    s[n][r] = v;
                }
            float alpha[4];
            #pragma unroll
            for (int r = 0; r < 4; r++) {
                float rm = fmaxf(fmaxf(s[0][r], s[1][r]), fmaxf(s[2][r], s[3][r]));
                rm = fmaxf(rm, __shfl_xor(rm, 1));
                rm = fmaxf(rm, __shfl_xor(rm, 2));
                rm = fmaxf(rm, __shfl_xor(rm, 4));
                rm = fmaxf(rm, __shfl_xor(rm, 8));
                float mn = fmaxf(mrow[r], rm);
                alpha[r] = __expf(mrow[r] - mn);
                mrow[r] = mn;
                float rs = 0.f;
                #pragma unroll
                for (int n = 0; n < 4; n++) {
                    float p = __expf(s[n][r] - mn);
                    s[n][r] = p;
                    rs += p;
                }
                rs += __shfl_xor(rs, 1);
                rs += __shfl_xor(rs, 2);
                rs += __shfl_xor(rs, 4);
                rs += __shfl_xor(rs, 8);
                lrow[r] = lrow[r] * alpha[r] + rs;
            }
            short* pw = &Ps[w * 16 * PPAD];
            #pragma unroll
            for (int n = 0; n < 4; n++)
                #pragma unroll
                for (int r = 0; r < 4; r++)
                    pw[(quad * 4 + r) * PPAD + n * 16 + col] = f2bs(s[n][r]);
            #pragma unroll
            for (int dt = 0; dt < 8; dt++)
                #pragma unroll
                for (int r = 0; r < 4; r++) o[dt][r] *= alpha[r];
            short8 ap0 = *(const short8*)&pw[col * PPAD + quad * 8];
            short8 ap1 = *(const short8*)&pw[col * PPAD + 32 + quad * 8];
            __builtin_amdgcn_s_setprio(1);
            #pragma unroll
            for (int dt = 0; dt < 8; dt++) {
                short8 bv0 = *(const short8*)(vt_base + (size_t)(dt * 16) * SS);
                o[dt] = __builtin_amdgcn_mfma_f32_16x16x32_bf16(ap0, bv0, o[dt], 0, 0, 0);
                short8 bv1 = *(const short8*)(vt_base + (size_t)(dt * 16) * SS + 32);
                o[dt] = __builtin_amdgcn_mfma_f32_16x16x32_bf16(ap1, bv1, o[dt], 0, 0, 0);
            }
            __builtin_amdgcn_s_setprio(0);
        }
        #pragma unroll
        for (int r = 0; r < 4; r++) {
            float inv = 1.f / lrow[r];
            int srow = q0 + w * 16 + quad * 4 + r;
            bf16* op = ao + ((size_t)(b * SS + srow) * NH + h) * DH;
            #pragma unroll
            for (int dt = 0; dt < 8; dt++)
                op[dt * 16 + col] = f2b(o[dt][r] * inv);
        }
    }
}

extern "C" void kernel_launch(void* const* d_in, const int* in_sizes, int n_in,
                              void* d_out, int out_size, void* d_ws, size_t ws_size,
                              hipStream_t stream) {
    const float* x  = (const float*)d_in[0];
    const float* fc = (const float*)d_in[1];
    const float* fs = (const float*)d_in[2];
    // d_in[3] = mask: exactly causal -> implemented directly
    const float* wq = (const float*)d_in[4];
    const float* wk = (const float*)d_in[5];
    const float* wv = (const float*)d_in[6];
    const float* wo = (const float*)d_in[7];
    float* out = (float*)d_out;

    const int M = BB * SS;  // 4096
    bf16* qkv    = (bf16*)d_ws;               // [0, 12582912)
    bf16* xb     = qkv + (size_t)M * QS;      // [12582912, 20971520)
    bf16* wqkvT  = xb + (size_t)M * DM;       // [20971520, 27262976)
    bf16* ao     = xb;                        // alias: xb dead after qkv GEMM
    bf16* vt     = wqkvT;                     // alias: wqkvT dead after qkv GEMM
    bf16* woT    = qkv;                       // alias: qkv dead after flash

    dim3 blk(256);
    convert_x<<<(M * DM / 4 + 255) / 256, blk, 0, stream>>>((const float4*)x, xb, M * DM / 4);
    convert_wT<<<dim3(DM / 64, DM / 64), blk, 0, stream>>>(wq, wqkvT, DM, DM);
    convert_wT<<<dim3((NKV * DH) / 64, DM / 64), blk, 0, stream>>>(wk, wqkvT + (size_t)2048 * DM, NKV * DH, DM);
    convert_wT<<<dim3((NKV * DH) / 64, DM / 64), blk, 0, stream>>>(wv, wqkvT + (size_t)2560 * DM, NKV * DH, DM);

    mfma_gemm<bf16><<<dim3(QS / 128, M / 128), blk, 0, stream>>>(xb, wqkvT, qkv, M, QS, DM);

    const int totq = BB * SS * NH * 64;
    const int totk = BB * SS * NKV * 64;
    rope_kernel<<<(totq + 255) / 256, blk, 0, stream>>>(qkv, fc, fs, NH, totq);
    rope_kernel<<<(totk + 255) / 256, blk, 0, stream>>>(qkv + 2048, fc, fs, NKV, totk);

    transpose_v<<<dim3(SS / 64, DH / 64, BB * NKV), blk, 0, stream>>>(qkv, vt);

    flash_attn<<<dim3(SS / 128, NH, BB), blk, 0, stream>>>(qkv, vt, ao);

    convert_wT<<<dim3(DM / 64, DM / 64), blk, 0, stream>>>(wo, woT, DM, DM);
    mfma_gemm<float><<<dim3(DM / 128, M / 128), blk, 0, stream>>>(ao, woT, out, M, DM, DM);
}

// Round 2
// 379.229 us; speedup vs baseline: 1.3891x; 1.3891x over previous
//
#include <hip/hip_runtime.h>
#include <hip/hip_bf16.h>

#define BB 2
#define SS 2048
#define DM 2048
#define NH 16
#define NKV 4
#define DH 128
#define QS 3072   // packed qkv row stride: 2048 q | 512 k | 512 v

typedef __hip_bfloat16 bf16;
typedef short short8 __attribute__((ext_vector_type(8)));
typedef float floatx4 __attribute__((ext_vector_type(4)));

__device__ __forceinline__ bf16 f2b(float v) { return __float2bfloat16(v); }
__device__ __forceinline__ short f2bs(float v) {
    bf16 t = __float2bfloat16(v);
    return __builtin_bit_cast(short, t);
}
__device__ __forceinline__ void store_c(bf16* p, float v) { *p = __float2bfloat16(v); }
__device__ __forceinline__ void store_c(float* p, float v) { *p = v; }

// ---------------- x fp32 -> bf16 (vectorized)
__global__ __launch_bounds__(256) void convert_x(const float4* __restrict__ x,
                                                 bf16* __restrict__ xb, int n4) {
    int i = blockIdx.x * blockDim.x + threadIdx.x;
    if (i >= n4) return;
    float4 v = x[i];
    bf16* p = xb + (size_t)i * 4;
    p[0] = f2b(v.x); p[1] = f2b(v.y); p[2] = f2b(v.z); p[3] = f2b(v.w);
}

// ---------------- weight fp32 [Kd][N] -> bf16 transposed [N][Kd]
__global__ __launch_bounds__(256) void convert_wT(const float* __restrict__ w,
                                                  bf16* __restrict__ outT,
                                                  int N, int Kd) {
    const int n0 = blockIdx.x * 64, k0 = blockIdx.y * 64;
    __shared__ float tile[64][65];
    const int tid = threadIdx.x;
    for (int i = tid; i < 4096; i += 256) {
        int r = i >> 6, c = i & 63;  // r: k-local, c: n-local
        tile[r][c] = w[(size_t)(k0 + r) * N + n0 + c];
    }
    __syncthreads();
    for (int i = tid; i < 4096; i += 256) {
        int r = i >> 6, c = i & 63;  // r: n-local, c: k-local
        outT[(size_t)(n0 + r) * Kd + k0 + c] = f2b(tile[c][r]);
    }
}

// ---------------- MFMA GEMM: C[M,N] = A[M,K] @ BT[N,K]^T, bf16 in, fp32 acc
// 128x128 tile, BK=32, 4 waves (2x2 of 64x64), 16x16x32 bf16 MFMA.
template <typename TC>
__global__ __launch_bounds__(256) void mfma_gemm(const bf16* __restrict__ A,
                                                 const bf16* __restrict__ BT,
                                                 TC* __restrict__ C,
                                                 int M, int N, int K) {
    __shared__ short As[128 * 32];
    __shared__ short Bs[128 * 32];
    const int tid = threadIdx.x;
    const int w = tid >> 6, lane = tid & 63;
    const int col16 = lane & 15, quad = lane >> 4;
    const int row0 = blockIdx.y * 128, col0 = blockIdx.x * 128;
    const int wr0 = (w >> 1) * 64, wc0 = (w & 1) * 64;

    floatx4 acc[4][4];
    #pragma unroll
    for (int mi = 0; mi < 4; mi++)
        #pragma unroll
        for (int ni = 0; ni < 4; ni++) acc[mi][ni] = (floatx4){0.f, 0.f, 0.f, 0.f};

    for (int k0 = 0; k0 < K; k0 += 32) {
        __syncthreads();
        #pragma unroll
        for (int it = 0; it < 2; it++) {
            int c = w * 128 + it * 64 + lane;
            int r = c >> 2, seg = c & 3;
            const bf16* g = A + (size_t)(row0 + r) * K + k0 + seg * 8;
            __builtin_amdgcn_global_load_lds(
                (const __attribute__((address_space(1))) unsigned int*)g,
                (__attribute__((address_space(3))) unsigned int*)&As[(w * 128 + it * 64) * 8],
                16, 0, 0);
        }
        #pragma unroll
        for (int it = 0; it < 2; it++) {
            int c = w * 128 + it * 64 + lane;
            int r = c >> 2, seg = c & 3;
            const bf16* g = BT + (size_t)(col0 + r) * K + k0 + seg * 8;
            __builtin_amdgcn_global_load_lds(
                (const __attribute__((address_space(1))) unsigned int*)g,
                (__attribute__((address_space(3))) unsigned int*)&Bs[(w * 128 + it * 64) * 8],
                16, 0, 0);
        }
        __syncthreads();

        short8 af[4], bfr[4];
        #pragma unroll
        for (int mi = 0; mi < 4; mi++)
            af[mi] = *(const short8*)&As[(wr0 + mi * 16 + col16) * 32 + quad * 8];
        #pragma unroll
        for (int ni = 0; ni < 4; ni++)
            bfr[ni] = *(const short8*)&Bs[(wc0 + ni * 16 + col16) * 32 + quad * 8];
        #pragma unroll
        for (int mi = 0; mi < 4; mi++)
            #pragma unroll
            for (int ni = 0; ni < 4; ni++)
                acc[mi][ni] = __builtin_amdgcn_mfma_f32_16x16x32_bf16(af[mi], bfr[ni], acc[mi][ni], 0, 0, 0);
    }
    #pragma unroll
    for (int mi = 0; mi < 4; mi++)
        #pragma unroll
        for (int ni = 0; ni < 4; ni++)
            #pragma unroll
            for (int r = 0; r < 4; r++)
                store_c(&C[(size_t)(row0 + wr0 + mi * 16 + quad * 4 + r) * N +
                           col0 + wc0 + ni * 16 + col16],
                        acc[mi][ni][r]);
}

// ---------------- RoPE (interleaved pairs) on packed qkv
__global__ void rope_kernel(bf16* __restrict__ base, const float* __restrict__ cs,
                            const float* __restrict__ sn, int n_heads, int total) {
    int idx = blockIdx.x * blockDim.x + threadIdx.x;
    if (idx >= total) return;
    int i = idx & 63;
    int h = (idx >> 6) % n_heads;
    size_t bs = (size_t)idx / (64 * n_heads);
    int s = (int)(bs % SS);
    float c = cs[s * 64 + i];
    float si = sn[s * 64 + i];
    bf16* p = base + bs * QS + h * DH + 2 * i;
    float xr = __bfloat162float(p[0]), xi = __bfloat162float(p[1]);
    p[0] = f2b(xr * c - xi * si);
    p[1] = f2b(xr * si + xi * c);
}

// ---------------- V transpose: qkv packed v -> vt[b][kvh][d][s]
__global__ __launch_bounds__(256) void transpose_v(const bf16* __restrict__ qkv,
                                                   bf16* __restrict__ vt) {
    const int s0 = blockIdx.x * 64, d0 = blockIdx.y * 64;
    const int b = blockIdx.z >> 2, kvh = blockIdx.z & 3;
    __shared__ bf16 tile[64][65];
    const int tid = threadIdx.x;
    for (int i = tid; i < 4096; i += 256) {
        int r = i >> 6, c = i & 63;
        tile[r][c] = qkv[(size_t)(b * SS + s0 + r) * QS + 2560 + kvh * DH + d0 + c];
    }
    __syncthreads();
    for (int i = tid; i < 4096; i += 256) {
        int r = i >> 6, c = i & 63;
        vt[((size_t)(b * NKV + kvh) * DH + d0 + r) * SS + s0 + c] = tile[c][r];
    }
}

// ---------------- Flash attention (causal, GQA), bf16 MFMA 16x16x32
// Round-2 structure: K/V staged in LDS (4-wave reuse — round 1 proved
// de-staging costs 2x), but staging is now:
//   * double-buffered, global_load_lds width=16 (fire-and-forget, no VGPR
//     roundtrip), issued right after the tile barrier so next-tile loads
//     fly under current-tile compute (T14 pattern);
//   * ONE __syncthreads per tile (was 2) — its implicit vmcnt(0) drains
//     loads that landed during the previous ~1.5K-cycle compute;
//   * bank-conflict-free via both-sides swizzle (rule #21): linear LDS
//     rows, 16B-segment index XOR'd with (row&7) on the global SOURCE at
//     stage time and on the ds_read address at consume time.
// Causal load-balance pairing: block bx processes Q-tile bx, then Q-tile
// (SS/64-1)-bx  =>  every block does exactly (SS/64)+1 = 33 K-tile iters.
#define PPAD 72

__global__ __launch_bounds__(256) void flash_attn(const bf16* __restrict__ qkv,
                                                  const bf16* __restrict__ vt,
                                                  bf16* __restrict__ ao) {
    const int bx = blockIdx.x, h = blockIdx.y, b = blockIdx.z;
    const int kvh = h >> 2;
    __shared__ short Ks[2][64 * 128];   // [kvrow][d-seg], swizzled segs
    __shared__ short Vs[2][128 * 64];   // [d-row][s-seg], swizzled segs
    __shared__ short Ps[4 * 16 * PPAD];
    const int tid = threadIdx.x;
    const int w = tid >> 6, lane = tid & 63;
    const int col = lane & 15, quad = lane >> 4;
    const int c7 = col & 7;
    const float scale = 0.08838834764831845f;

    // staging lane decomposition (dest LDS is linear: base + lane*16B)
    const int krl = lane >> 4, kseg = lane & 15;   // K: 4 rows / inst
    const int vrl = lane >> 3, vseg = lane & 7;    // V: 8 rows / inst

    const bf16* kgb = qkv + (size_t)b * SS * QS + 2048 + kvh * DH;
    const bf16* vgb = vt + (size_t)(b * NKV + kvh) * DH * SS;

    for (int phase = 0; phase < 2; phase++) {
        const int qt = phase == 0 ? bx : (SS / 64 - 1 - bx);
        const int q0 = qt * 64;

        short8 aq[4];
        const bf16* qbase = qkv + (size_t)(b * SS + q0 + w * 16 + col) * QS + h * DH;
        #pragma unroll
        for (int kc = 0; kc < 4; kc++)
            aq[kc] = *(const short8*)(qbase + kc * 32 + quad * 8);

        floatx4 o[8];
        #pragma unroll
        for (int dt = 0; dt < 8; dt++) o[dt] = (floatx4){0.f, 0.f, 0.f, 0.f};
        float mrow[4] = {-3e38f, -3e38f, -3e38f, -3e38f};
        float lrow[4] = {0.f, 0.f, 0.f, 0.f};

        for (int kt = 0; kt <= qt; kt++) {
            const int cur = kt & 1;
            __syncthreads();  // waves done reading buf[cur^1]; own prefetch drained
            if (kt == 0) {
                // synchronous stage of tile 0 into buf 0
                #pragma unroll
                for (int it = 0; it < 4; it++) {
                    int row = w * 16 + it * 4 + krl;
                    const bf16* g = kgb + (size_t)row * QS + ((kseg ^ (row & 7)) * 8);
                    __builtin_amdgcn_global_load_lds(
                        (const __attribute__((address_space(1))) unsigned int*)g,
                        (__attribute__((address_space(3))) unsigned int*)&Ks[0][(w * 16 + it * 4) * 128],
                        16, 0, 0);
                }
                #pragma unroll
                for (int it = 0; it < 4; it++) {
                    int drow = w * 32 + it * 8 + vrl;
                    const bf16* g = vgb + (size_t)drow * SS + ((vseg ^ (drow & 7)) * 8);
                    __builtin_amdgcn_global_load_lds(
                        (const __attribute__((address_space(1))) unsigned int*)g,
                        (__attribute__((address_space(3))) unsigned int*)&Vs[0][(w * 32 + it * 8) * 64],
                        16, 0, 0);
                }
                __syncthreads();
            }
            if (kt < qt) {
                // prefetch tile kt+1 into buf[cur^1]; overlaps compute below
                const int nk0 = (kt + 1) * 64;
                #pragma unroll
                for (int it = 0; it < 4; it++) {
                    int row = w * 16 + it * 4 + krl;
                    const bf16* g = kgb + (size_t)(nk0 + row) * QS + ((kseg ^ (row & 7)) * 8);
                    __builtin_amdgcn_global_load_lds(
                        (const __attribute__((address_space(1))) unsigned int*)g,
                        (__attribute__((address_space(3))) unsigned int*)&Ks[cur ^ 1][(w * 16 + it * 4) * 128],
                        16, 0, 0);
                }
                #pragma unroll
                for (int it = 0; it < 4; it++) {
                    int drow = w * 32 + it * 8 + vrl;
                    const bf16* g = vgb + (size_t)drow * SS + nk0 + ((vseg ^ (drow & 7)) * 8);
                    __builtin_amdgcn_global_load_lds(
                        (const __attribute__((address_space(1))) unsigned int*)g,
                        (__attribute__((address_space(3))) unsigned int*)&Vs[cur ^ 1][(w * 32 + it * 8) * 64],
                        16, 0, 0);
                }
            }

            const int k0 = kt * 64;
            floatx4 s[4];
            __builtin_amdgcn_s_setprio(1);
            #pragma unroll
            for (int n = 0; n < 4; n++) {
                s[n] = (floatx4){0.f, 0.f, 0.f, 0.f};
                #pragma unroll
                for (int kc = 0; kc < 4; kc++) {
                    short8 bk = *(const short8*)&Ks[cur][(n * 16 + col) * 128 + (((kc * 4 + quad) ^ c7) * 8)];
                    s[n] = __builtin_amdgcn_mfma_f32_16x16x32_bf16(aq[kc], bk, s[n], 0, 0, 0);
                }
            }
            __builtin_amdgcn_s_setprio(0);

            #pragma unroll
            for (int n = 0; n < 4; n++)
                #pragma unroll
                for (int r = 0; r < 4; r++) {
                    float v = s[n][r] * scale;
                    if (kt == qt && (k0 + n * 16 + col) > (q0 + w * 16 + quad * 4 + r)) v = -3e38f;
                    s[n][r] = v;
                }
            float alpha[4];
            #pragma unroll
            for (int r = 0; r < 4; r++) {
                float rm = fmaxf(fmaxf(s[0][r], s[1][r]), fmaxf(s[2][r], s[3][r]));
                rm = fmaxf(rm, __shfl_xor(rm, 1));
                rm = fmaxf(rm, __shfl_xor(rm, 2));
                rm = fmaxf(rm, __shfl_xor(rm, 4));
                rm = fmaxf(rm, __shfl_xor(rm, 8));
                float mn = fmaxf(mrow[r], rm);
                alpha[r] = __expf(mrow[r] - mn);
                mrow[r] = mn;
                float rs = 0.f;
                #pragma unroll
                for (int n = 0; n < 4; n++) {
                    float p = __expf(s[n][r] - mn);
                    s[n][r] = p;
                    rs += p;
                }
                rs += __shfl_xor(rs, 1);
                rs += __shfl_xor(rs, 2);
                rs += __shfl_xor(rs, 4);
                rs += __shfl_xor(rs, 8);
                lrow[r] = lrow[r] * alpha[r] + rs;
            }
            short* pw = &Ps[w * 16 * PPAD];
            #pragma unroll
            for (int n = 0; n < 4; n++)
                #pragma unroll
                for (int r = 0; r < 4; r++)
                    pw[(quad * 4 + r) * PPAD + n * 16 + col] = f2bs(s[n][r]);
            #pragma unroll
            for (int dt = 0; dt < 8; dt++)
                #pragma unroll
                for (int r = 0; r < 4; r++) o[dt][r] *= alpha[r];
            short8 ap0 = *(const short8*)&pw[col * PPAD + quad * 8];
            short8 ap1 = *(const short8*)&pw[col * PPAD + 32 + quad * 8];
            __builtin_amdgcn_s_setprio(1);
            #pragma unroll
            for (int dt = 0; dt < 8; dt++) {
                short8 bv0 = *(const short8*)&Vs[cur][(dt * 16 + col) * 64 + ((quad ^ c7) * 8)];
                o[dt] = __builtin_amdgcn_mfma_f32_16x16x32_bf16(ap0, bv0, o[dt], 0, 0, 0);
                short8 bv1 = *(const short8*)&Vs[cur][(dt * 16 + col) * 64 + (((quad + 4) ^ c7) * 8)];
                o[dt] = __builtin_amdgcn_mfma_f32_16x16x32_bf16(ap1, bv1, o[dt], 0, 0, 0);
            }
            __builtin_amdgcn_s_setprio(0);
        }
        #pragma unroll
        for (int r = 0; r < 4; r++) {
            float inv = 1.f / lrow[r];
            int srow = q0 + w * 16 + quad * 4 + r;
            bf16* op = ao + ((size_t)(b * SS + srow) * NH + h) * DH;
            #pragma unroll
            for (int dt = 0; dt < 8; dt++)
                op[dt * 16 + col] = f2b(o[dt][r] * inv);
        }
    }
}

extern "C" void kernel_launch(void* const* d_in, const int* in_sizes, int n_in,
                              void* d_out, int out_size, void* d_ws, size_t ws_size,
                              hipStream_t stream) {
    const float* x  = (const float*)d_in[0];
    const float* fc = (const float*)d_in[1];
    const float* fs = (const float*)d_in[2];
    // d_in[3] = mask: exactly causal -> implemented directly
    const float* wq = (const float*)d_in[4];
    const float* wk = (const float*)d_in[5];
    const float* wv = (const float*)d_in[6];
    const float* wo = (const float*)d_in[7];
    float* out = (float*)d_out;

    const int M = BB * SS;  // 4096
    bf16* qkv    = (bf16*)d_ws;               // [0, 12582912)
    bf16* xb     = qkv + (size_t)M * QS;      // [12582912, 20971520)
    bf16* wqkvT  = xb + (size_t)M * DM;       // [20971520, 27262976)
    bf16* ao     = xb;                        // alias: xb dead after qkv GEMM
    bf16* vt     = wqkvT;                     // alias: wqkvT dead after qkv GEMM
    bf16* woT    = qkv;                       // alias: qkv dead after flash

    dim3 blk(256);
    convert_x<<<(M * DM / 4 + 255) / 256, blk, 0, stream>>>((const float4*)x, xb, M * DM / 4);
    convert_wT<<<dim3(DM / 64, DM / 64), blk, 0, stream>>>(wq, wqkvT, DM, DM);
    convert_wT<<<dim3((NKV * DH) / 64, DM / 64), blk, 0, stream>>>(wk, wqkvT + (size_t)2048 * DM, NKV * DH, DM);
    convert_wT<<<dim3((NKV * DH) / 64, DM / 64), blk, 0, stream>>>(wv, wqkvT + (size_t)2560 * DM, NKV * DH, DM);

    mfma_gemm<bf16><<<dim3(QS / 128, M / 128), blk, 0, stream>>>(xb, wqkvT, qkv, M, QS, DM);

    const int totq = BB * SS * NH * 64;
    const int totk = BB * SS * NKV * 64;
    rope_kernel<<<(totq + 255) / 256, blk, 0, stream>>>(qkv, fc, fs, NH, totq);
    rope_kernel<<<(totk + 255) / 256, blk, 0, stream>>>(qkv + 2048, fc, fs, NKV, totk);

    transpose_v<<<dim3(SS / 64, DH / 64, BB * NKV), blk, 0, stream>>>(qkv, vt);

    flash_attn<<<dim3(SS / 128, NH, BB), blk, 0, stream>>>(qkv, vt, ao);

    convert_wT<<<dim3(DM / 64, DM / 64), blk, 0, stream>>>(wo, woT, DM, DM);
    mfma_gemm<float><<<dim3(DM / 128, M / 128), blk, 0, stream>>>(ao, woT, out, M, DM, DM);
}

// Round 3
// 366.325 us; speedup vs baseline: 1.4380x; 1.0352x over previous
//
#include <hip/hip_runtime.h>
#include <hip/hip_bf16.h>

#define BB 2
#define SS 2048
#define DM 2048
#define NH 16
#define NKV 4
#define DH 128
#define QS 3072   // packed qkv row stride: 2048 q | 512 k | 512 v

typedef __hip_bfloat16 bf16;
typedef short short8 __attribute__((ext_vector_type(8)));
typedef float floatx4 __attribute__((ext_vector_type(4)));

#if __has_builtin(__builtin_amdgcn_exp2f)
#define EX2(x) __builtin_amdgcn_exp2f(x)
#else
#define EX2(x) exp2f(x)
#endif

__device__ __forceinline__ bf16 f2b(float v) { return __float2bfloat16(v); }
__device__ __forceinline__ short f2bs(float v) {
    bf16 t = __float2bfloat16(v);
    return __builtin_bit_cast(short, t);
}
__device__ __forceinline__ void store_c(bf16* p, float v) { *p = __float2bfloat16(v); }
__device__ __forceinline__ void store_c(float* p, float v) { *p = v; }

// ---------------- x fp32 -> bf16 (vectorized)
__global__ __launch_bounds__(256) void convert_x(const float4* __restrict__ x,
                                                 bf16* __restrict__ xb, int n4) {
    int i = blockIdx.x * blockDim.x + threadIdx.x;
    if (i >= n4) return;
    float4 v = x[i];
    bf16* p = xb + (size_t)i * 4;
    p[0] = f2b(v.x); p[1] = f2b(v.y); p[2] = f2b(v.z); p[3] = f2b(v.w);
}

// ---------------- weight fp32 [Kd][N] -> bf16 transposed [N][Kd]
__global__ __launch_bounds__(256) void convert_wT(const float* __restrict__ w,
                                                  bf16* __restrict__ outT,
                                                  int N, int Kd) {
    const int n0 = blockIdx.x * 64, k0 = blockIdx.y * 64;
    __shared__ float tile[64][65];
    const int tid = threadIdx.x;
    for (int i = tid; i < 4096; i += 256) {
        int r = i >> 6, c = i & 63;  // r: k-local, c: n-local
        tile[r][c] = w[(size_t)(k0 + r) * N + n0 + c];
    }
    __syncthreads();
    for (int i = tid; i < 4096; i += 256) {
        int r = i >> 6, c = i & 63;  // r: n-local, c: k-local
        outT[(size_t)(n0 + r) * Kd + k0 + c] = f2b(tile[c][r]);
    }
}

// ---------------- MFMA GEMM: C[M,N] = A[M,K] @ BT[N,K]^T, bf16 in, fp32 acc
// 128x128 tile, BK=32, 4 waves (2x2 of 64x64), 16x16x32 bf16 MFMA.
template <typename TC>
__global__ __launch_bounds__(256) void mfma_gemm(const bf16* __restrict__ A,
                                                 const bf16* __restrict__ BT,
                                                 TC* __restrict__ C,
                                                 int M, int N, int K) {
    __shared__ short As[128 * 32];
    __shared__ short Bs[128 * 32];
    const int tid = threadIdx.x;
    const int w = tid >> 6, lane = tid & 63;
    const int col16 = lane & 15, quad = lane >> 4;
    const int row0 = blockIdx.y * 128, col0 = blockIdx.x * 128;
    const int wr0 = (w >> 1) * 64, wc0 = (w & 1) * 64;

    floatx4 acc[4][4];
    #pragma unroll
    for (int mi = 0; mi < 4; mi++)
        #pragma unroll
        for (int ni = 0; ni < 4; ni++) acc[mi][ni] = (floatx4){0.f, 0.f, 0.f, 0.f};

    for (int k0 = 0; k0 < K; k0 += 32) {
        __syncthreads();
        #pragma unroll
        for (int it = 0; it < 2; it++) {
            int c = w * 128 + it * 64 + lane;
            int r = c >> 2, seg = c & 3;
            const bf16* g = A + (size_t)(row0 + r) * K + k0 + seg * 8;
            __builtin_amdgcn_global_load_lds(
                (const __attribute__((address_space(1))) unsigned int*)g,
                (__attribute__((address_space(3))) unsigned int*)&As[(w * 128 + it * 64) * 8],
                16, 0, 0);
        }
        #pragma unroll
        for (int it = 0; it < 2; it++) {
            int c = w * 128 + it * 64 + lane;
            int r = c >> 2, seg = c & 3;
            const bf16* g = BT + (size_t)(col0 + r) * K + k0 + seg * 8;
            __builtin_amdgcn_global_load_lds(
                (const __attribute__((address_space(1))) unsigned int*)g,
                (__attribute__((address_space(3))) unsigned int*)&Bs[(w * 128 + it * 64) * 8],
                16, 0, 0);
        }
        __syncthreads();

        short8 af[4], bfr[4];
        #pragma unroll
        for (int mi = 0; mi < 4; mi++)
            af[mi] = *(const short8*)&As[(wr0 + mi * 16 + col16) * 32 + quad * 8];
        #pragma unroll
        for (int ni = 0; ni < 4; ni++)
            bfr[ni] = *(const short8*)&Bs[(wc0 + ni * 16 + col16) * 32 + quad * 8];
        #pragma unroll
        for (int mi = 0; mi < 4; mi++)
            #pragma unroll
            for (int ni = 0; ni < 4; ni++)
                acc[mi][ni] = __builtin_amdgcn_mfma_f32_16x16x32_bf16(af[mi], bfr[ni], acc[mi][ni], 0, 0, 0);
    }
    #pragma unroll
    for (int mi = 0; mi < 4; mi++)
        #pragma unroll
        for (int ni = 0; ni < 4; ni++)
            #pragma unroll
            for (int r = 0; r < 4; r++)
                store_c(&C[(size_t)(row0 + wr0 + mi * 16 + quad * 4 + r) * N +
                           col0 + wc0 + ni * 16 + col16],
                        acc[mi][ni][r]);
}

// ---------------- RoPE (interleaved pairs) on packed qkv
__global__ void rope_kernel(bf16* __restrict__ base, const float* __restrict__ cs,
                            const float* __restrict__ sn, int n_heads, int total) {
    int idx = blockIdx.x * blockDim.x + threadIdx.x;
    if (idx >= total) return;
    int i = idx & 63;
    int h = (idx >> 6) % n_heads;
    size_t bs = (size_t)idx / (64 * n_heads);
    int s = (int)(bs % SS);
    float c = cs[s * 64 + i];
    float si = sn[s * 64 + i];
    bf16* p = base + bs * QS + h * DH + 2 * i;
    float xr = __bfloat162float(p[0]), xi = __bfloat162float(p[1]);
    p[0] = f2b(xr * c - xi * si);
    p[1] = f2b(xr * si + xi * c);
}

// ---------------- V transpose: qkv packed v -> vt[b][kvh][d][s]
__global__ __launch_bounds__(256) void transpose_v(const bf16* __restrict__ qkv,
                                                   bf16* __restrict__ vt) {
    const int s0 = blockIdx.x * 64, d0 = blockIdx.y * 64;
    const int b = blockIdx.z >> 2, kvh = blockIdx.z & 3;
    __shared__ bf16 tile[64][65];
    const int tid = threadIdx.x;
    for (int i = tid; i < 4096; i += 256) {
        int r = i >> 6, c = i & 63;
        tile[r][c] = qkv[(size_t)(b * SS + s0 + r) * QS + 2560 + kvh * DH + d0 + c];
    }
    __syncthreads();
    for (int i = tid; i < 4096; i += 256) {
        int r = i >> 6, c = i & 63;
        vt[((size_t)(b * NKV + kvh) * DH + d0 + r) * SS + s0 + c] = tile[c][r];
    }
}

// ---------------- Flash attention (causal, GQA), bf16 MFMA 16x16x32
// Round-3: VALU diet on the softmax epilogue (was VALUBusy 40% vs MfmaUtil 13%):
//   * row-sum via MFMA ones-column: lrow == P @ ones, an extra PV accumulator
//     with a constant all-ones B-frag. C/D layout broadcasts the row-sum to
//     every lane -> zero shuffle/adds, same x alpha recurrence as o.
//     Denominator now sums the same bf16 P that multiplies V (consistent).
//   * raw-score units: scale folded into exp2: p = exp2(s*C - m*C),
//     C = scale*log2e. Kills 16 muls + 16 subs per tile.
//   * causal mask hoisted under uniform if(kt==qt).
//   * defer-rescale (T13, THR=0 exact): wave-vote skip of alpha/rescale when
//     running max did not grow.
// Staging structure from round 2 (proven): K/V double-buffered via
// global_load_lds w=16, one barrier/tile, both-sides XOR swizzle.
// Causal load-balance pairing: block bx processes Q-tile bx, then Q-tile
// (SS/64-1)-bx  =>  every block does exactly (SS/64)+1 = 33 K-tile iters.
#define PPAD 72

__global__ __launch_bounds__(256) void flash_attn(const bf16* __restrict__ qkv,
                                                  const bf16* __restrict__ vt,
                                                  bf16* __restrict__ ao) {
    const int bx = blockIdx.x, h = blockIdx.y, b = blockIdx.z;
    const int kvh = h >> 2;
    __shared__ short Ks[2][64 * 128];   // [kvrow][d-seg], swizzled segs
    __shared__ short Vs[2][128 * 64];   // [d-row][s-seg], swizzled segs
    __shared__ short Ps[4 * 16 * PPAD];
    const int tid = threadIdx.x;
    const int w = tid >> 6, lane = tid & 63;
    const int col = lane & 15, quad = lane >> 4;
    const int c7 = col & 7;
    const float C = 0.12751746517859245f;  // (1/sqrt(128)) * log2(e)

    // staging lane decomposition (dest LDS is linear: base + lane*16B)
    const int krl = lane >> 4, kseg = lane & 15;   // K: 4 rows / inst
    const int vrl = lane >> 3, vseg = lane & 7;    // V: 8 rows / inst

    const bf16* kgb = qkv + (size_t)b * SS * QS + 2048 + kvh * DH;
    const bf16* vgb = vt + (size_t)(b * NKV + kvh) * DH * SS;

    const short8 vone = {0x3F80, 0x3F80, 0x3F80, 0x3F80, 0x3F80, 0x3F80, 0x3F80, 0x3F80};

    for (int phase = 0; phase < 2; phase++) {
        const int qt = phase == 0 ? bx : (SS / 64 - 1 - bx);
        const int q0 = qt * 64;

        short8 aq[4];
        const bf16* qbase = qkv + (size_t)(b * SS + q0 + w * 16 + col) * QS + h * DH;
        #pragma unroll
        for (int kc = 0; kc < 4; kc++)
            aq[kc] = *(const short8*)(qbase + kc * 32 + quad * 8);

        floatx4 o[8];
        #pragma unroll
        for (int dt = 0; dt < 8; dt++) o[dt] = (floatx4){0.f, 0.f, 0.f, 0.f};
        floatx4 oL = (floatx4){0.f, 0.f, 0.f, 0.f};   // row-sum accumulator (denominator)
        float mrow[4] = {-3e38f, -3e38f, -3e38f, -3e38f};

        for (int kt = 0; kt <= qt; kt++) {
            const int cur = kt & 1;
            __syncthreads();  // waves done reading buf[cur^1]; own prefetch drained
            if (kt == 0) {
                // synchronous stage of tile 0 into buf 0
                #pragma unroll
                for (int it = 0; it < 4; it++) {
                    int row = w * 16 + it * 4 + krl;
                    const bf16* g = kgb + (size_t)row * QS + ((kseg ^ (row & 7)) * 8);
                    __builtin_amdgcn_global_load_lds(
                        (const __attribute__((address_space(1))) unsigned int*)g,
                        (__attribute__((address_space(3))) unsigned int*)&Ks[0][(w * 16 + it * 4) * 128],
                        16, 0, 0);
                }
                #pragma unroll
                for (int it = 0; it < 4; it++) {
                    int drow = w * 32 + it * 8 + vrl;
                    const bf16* g = vgb + (size_t)drow * SS + ((vseg ^ (drow & 7)) * 8);
                    __builtin_amdgcn_global_load_lds(
                        (const __attribute__((address_space(1))) unsigned int*)g,
                        (__attribute__((address_space(3))) unsigned int*)&Vs[0][(w * 32 + it * 8) * 64],
                        16, 0, 0);
                }
                __syncthreads();
            }
            if (kt < qt) {
                // prefetch tile kt+1 into buf[cur^1]; overlaps compute below
                const int nk0 = (kt + 1) * 64;
                #pragma unroll
                for (int it = 0; it < 4; it++) {
                    int row = w * 16 + it * 4 + krl;
                    const bf16* g = kgb + (size_t)(nk0 + row) * QS + ((kseg ^ (row & 7)) * 8);
                    __builtin_amdgcn_global_load_lds(
                        (const __attribute__((address_space(1))) unsigned int*)g,
                        (__attribute__((address_space(3))) unsigned int*)&Ks[cur ^ 1][(w * 16 + it * 4) * 128],
                        16, 0, 0);
                }
                #pragma unroll
                for (int it = 0; it < 4; it++) {
                    int drow = w * 32 + it * 8 + vrl;
                    const bf16* g = vgb + (size_t)drow * SS + nk0 + ((vseg ^ (drow & 7)) * 8);
                    __builtin_amdgcn_global_load_lds(
                        (const __attribute__((address_space(1))) unsigned int*)g,
                        (__attribute__((address_space(3))) unsigned int*)&Vs[cur ^ 1][(w * 32 + it * 8) * 64],
                        16, 0, 0);
                }
            }

            const int k0 = kt * 64;
            floatx4 s[4];
            __builtin_amdgcn_s_setprio(1);
            #pragma unroll
            for (int n = 0; n < 4; n++) {
                s[n] = (floatx4){0.f, 0.f, 0.f, 0.f};
                #pragma unroll
                for (int kc = 0; kc < 4; kc++) {
                    short8 bk = *(const short8*)&Ks[cur][(n * 16 + col) * 128 + (((kc * 4 + quad) ^ c7) * 8)];
                    s[n] = __builtin_amdgcn_mfma_f32_16x16x32_bf16(aq[kc], bk, s[n], 0, 0, 0);
                }
            }
            __builtin_amdgcn_s_setprio(0);

            // causal mask: uniform branch, raw units
            if (kt == qt) {
                #pragma unroll
                for (int n = 0; n < 4; n++)
                    #pragma unroll
                    for (int r = 0; r < 4; r++)
                        if ((k0 + n * 16 + col) > (q0 + w * 16 + quad * 4 + r)) s[n][r] = -3e38f;
            }

            // row max (raw units); rows live in 16-lane groups (fixed quad)
            float rmx[4];
            #pragma unroll
            for (int r = 0; r < 4; r++) {
                float rm = fmaxf(fmaxf(s[0][r], s[1][r]), fmaxf(s[2][r], s[3][r]));
                rm = fmaxf(rm, __shfl_xor(rm, 1));
                rm = fmaxf(rm, __shfl_xor(rm, 2));
                rm = fmaxf(rm, __shfl_xor(rm, 4));
                rm = fmaxf(rm, __shfl_xor(rm, 8));
                rmx[r] = fmaxf(rm, mrow[r]);
            }
            // defer-rescale: skip alpha path when no row max grew (wave vote)
            bool grow = (rmx[0] > mrow[0]) | (rmx[1] > mrow[1]) |
                        (rmx[2] > mrow[2]) | (rmx[3] > mrow[3]);
            if (__any((int)grow)) {
                float al[4];
                #pragma unroll
                for (int r = 0; r < 4; r++) {
                    al[r] = EX2((mrow[r] - rmx[r]) * C);
                    mrow[r] = rmx[r];
                }
                #pragma unroll
                for (int dt = 0; dt < 8; dt++)
                    #pragma unroll
                    for (int r = 0; r < 4; r++) o[dt][r] *= al[r];
                #pragma unroll
                for (int r = 0; r < 4; r++) oL[r] *= al[r];
            }
            float mC[4];
            #pragma unroll
            for (int r = 0; r < 4; r++) mC[r] = mrow[r] * C;

            // P = exp2(s*C - m*C) -> bf16 -> Ps
            short* pw = &Ps[w * 16 * PPAD];
            #pragma unroll
            for (int n = 0; n < 4; n++)
                #pragma unroll
                for (int r = 0; r < 4; r++)
                    pw[(quad * 4 + r) * PPAD + n * 16 + col] =
                        f2bs(EX2(__builtin_fmaf(s[n][r], C, -mC[r])));

            short8 ap0 = *(const short8*)&pw[col * PPAD + quad * 8];
            short8 ap1 = *(const short8*)&pw[col * PPAD + 32 + quad * 8];
            __builtin_amdgcn_s_setprio(1);
            #pragma unroll
            for (int dt = 0; dt < 8; dt++) {
                short8 bv0 = *(const short8*)&Vs[cur][(dt * 16 + col) * 64 + ((quad ^ c7) * 8)];
                o[dt] = __builtin_amdgcn_mfma_f32_16x16x32_bf16(ap0, bv0, o[dt], 0, 0, 0);
                short8 bv1 = *(const short8*)&Vs[cur][(dt * 16 + col) * 64 + (((quad + 4) ^ c7) * 8)];
                o[dt] = __builtin_amdgcn_mfma_f32_16x16x32_bf16(ap1, bv1, o[dt], 0, 0, 0);
            }
            // denominator: row-sum of P via ones-column MFMA (broadcast to all lanes)
            oL = __builtin_amdgcn_mfma_f32_16x16x32_bf16(ap0, vone, oL, 0, 0, 0);
            oL = __builtin_amdgcn_mfma_f32_16x16x32_bf16(ap1, vone, oL, 0, 0, 0);
            __builtin_amdgcn_s_setprio(0);
        }
        #pragma unroll
        for (int r = 0; r < 4; r++) {
            float inv = 1.f / oL[r];
            int srow = q0 + w * 16 + quad * 4 + r;
            bf16* op = ao + ((size_t)(b * SS + srow) * NH + h) * DH;
            #pragma unroll
            for (int dt = 0; dt < 8; dt++)
                op[dt * 16 + col] = f2b(o[dt][r] * inv);
        }
    }
}

extern "C" void kernel_launch(void* const* d_in, const int* in_sizes, int n_in,
                              void* d_out, int out_size, void* d_ws, size_t ws_size,
                              hipStream_t stream) {
    const float* x  = (const float*)d_in[0];
    const float* fc = (const float*)d_in[1];
    const float* fs = (const float*)d_in[2];
    // d_in[3] = mask: exactly causal -> implemented directly
    const float* wq = (const float*)d_in[4];
    const float* wk = (const float*)d_in[5];
    const float* wv = (const float*)d_in[6];
    const float* wo = (const float*)d_in[7];
    float* out = (float*)d_out;

    const int M = BB * SS;  // 4096
    bf16* qkv    = (bf16*)d_ws;               // [0, 12582912)
    bf16* xb     = qkv + (size_t)M * QS;      // [12582912, 20971520)
    bf16* wqkvT  = xb + (size_t)M * DM;       // [20971520, 27262976)
    bf16* ao     = xb;                        // alias: xb dead after qkv GEMM
    bf16* vt     = wqkvT;                     // alias: wqkvT dead after qkv GEMM
    bf16* woT    = qkv;                       // alias: qkv dead after flash

    dim3 blk(256);
    convert_x<<<(M * DM / 4 + 255) / 256, blk, 0, stream>>>((const float4*)x, xb, M * DM / 4);
    convert_wT<<<dim3(DM / 64, DM / 64), blk, 0, stream>>>(wq, wqkvT, DM, DM);
    convert_wT<<<dim3((NKV * DH) / 64, DM / 64), blk, 0, stream>>>(wk, wqkvT + (size_t)2048 * DM, NKV * DH, DM);
    convert_wT<<<dim3((NKV * DH) / 64, DM / 64), blk, 0, stream>>>(wv, wqkvT + (size_t)2560 * DM, NKV * DH, DM);

    mfma_gemm<bf16><<<dim3(QS / 128, M / 128), blk, 0, stream>>>(xb, wqkvT, qkv, M, QS, DM);

    const int totq = BB * SS * NH * 64;
    const int totk = BB * SS * NKV * 64;
    rope_kernel<<<(totq + 255) / 256, blk, 0, stream>>>(qkv, fc, fs, NH, totq);
    rope_kernel<<<(totk + 255) / 256, blk, 0, stream>>>(qkv + 2048, fc, fs, NKV, totk);

    transpose_v<<<dim3(SS / 64, DH / 64, BB * NKV), blk, 0, stream>>>(qkv, vt);

    flash_attn<<<dim3(SS / 128, NH, BB), blk, 0, stream>>>(qkv, vt, ao);

    convert_wT<<<dim3(DM / 64, DM / 64), blk, 0, stream>>>(wo, woT, DM, DM);
    mfma_gemm<float><<<dim3(DM / 128, M / 128), blk, 0, stream>>>(ao, woT, out, M, DM, DM);
}

// Round 4
// 345.464 us; speedup vs baseline: 1.5248x; 1.0604x over previous
//
#include <hip/hip_runtime.h>
#include <hip/hip_bf16.h>

#define BB 2
#define SS 2048
#define DM 2048
#define NH 16
#define NKV 4
#define DH 128
#define QS 3072   // packed qkv row stride: 2048 q | 512 k | 512 v

typedef __hip_bfloat16 bf16;
typedef short short8 __attribute__((ext_vector_type(8)));
typedef float floatx4 __attribute__((ext_vector_type(4)));

#if __has_builtin(__builtin_amdgcn_exp2f)
#define EX2(x) __builtin_amdgcn_exp2f(x)
#else
#define EX2(x) exp2f(x)
#endif

__device__ __forceinline__ bf16 f2b(float v) { return __float2bfloat16(v); }
__device__ __forceinline__ short f2bs(float v) {
    bf16 t = __float2bfloat16(v);
    return __builtin_bit_cast(short, t);
}
__device__ __forceinline__ void store_c(bf16* p, float v) { *p = __float2bfloat16(v); }
__device__ __forceinline__ void store_c(float* p, float v) { *p = v; }

// ---------------- x fp32 -> bf16 (vectorized)
__global__ __launch_bounds__(256) void convert_x(const float4* __restrict__ x,
                                                 bf16* __restrict__ xb, int n4) {
    int i = blockIdx.x * blockDim.x + threadIdx.x;
    if (i >= n4) return;
    float4 v = x[i];
    bf16* p = xb + (size_t)i * 4;
    p[0] = f2b(v.x); p[1] = f2b(v.y); p[2] = f2b(v.z); p[3] = f2b(v.w);
}

// ---------------- weight fp32 [Kd][N] -> bf16 transposed [N][Kd] (wo path)
__global__ __launch_bounds__(256) void convert_wT(const float* __restrict__ w,
                                                  bf16* __restrict__ outT,
                                                  int N, int Kd) {
    const int n0 = blockIdx.x * 64, k0 = blockIdx.y * 64;
    __shared__ float tile[64][65];
    const int tid = threadIdx.x;
    for (int i = tid; i < 4096; i += 256) {
        int r = i >> 6, c = i & 63;  // r: k-local, c: n-local
        tile[r][c] = w[(size_t)(k0 + r) * N + n0 + c];
    }
    __syncthreads();
    for (int i = tid; i < 4096; i += 256) {
        int r = i >> 6, c = i & 63;  // r: n-local, c: k-local
        outT[(size_t)(n0 + r) * Kd + k0 + c] = f2b(tile[c][r]);
    }
}

// ---------------- fused wq|wk|wv fp32 -> bf16 transposed into wqkvT[3072][2048]
__global__ __launch_bounds__(256) void convert_wqkv(const float* __restrict__ wq,
                                                    const float* __restrict__ wk,
                                                    const float* __restrict__ wv,
                                                    bf16* __restrict__ outT) {
    const int bx = blockIdx.x;            // 48 col-tiles of the packed output
    const float* w; int N; int n0;
    if (bx < 32)      { w = wq; N = 2048; n0 = bx * 64; }
    else if (bx < 40) { w = wk; N = 512;  n0 = (bx - 32) * 64; }
    else              { w = wv; N = 512;  n0 = (bx - 40) * 64; }
    const int k0 = blockIdx.y * 64;
    const int gn0 = bx * 64;              // row in packed outT
    __shared__ float tile[64][65];
    const int tid = threadIdx.x;
    for (int i = tid; i < 4096; i += 256) {
        int r = i >> 6, c = i & 63;
        tile[r][c] = w[(size_t)(k0 + r) * N + n0 + c];
    }
    __syncthreads();
    for (int i = tid; i < 4096; i += 256) {
        int r = i >> 6, c = i & 63;
        outT[(size_t)(gn0 + r) * DM + k0 + c] = f2b(tile[c][r]);
    }
}

// ---------------- MFMA GEMM: C[M,N] = A[M,K] @ BT[N,K]^T, bf16 in, fp32 acc
// Round-4 schedule (T4 counted-vmcnt, 2-deep prefetch):
//   * triple-buffered 128x32 A/B tiles (48 KB LDS), gload_lds w=16;
//   * per iter: vmcnt(4) [tile t's 4 loads retired, tile t+1's stay in
//     flight] -> raw s_barrier -> issue tile t+2 -> ds_read -> MFMA.
//     Never vmcnt(0) in the main loop; each load gets ~2 iters to land.
//   * both-sides seg-XOR swizzle (seg ^= row&3 at stage source + read):
//     8-way -> 4-way bank conflicts on the b128 fragment reads.
// Race argument: a wave's iter t-1 ds_reads complete before its MFMAs,
// hence before it reaches the iter-t barrier; so after that barrier
// buf[(t+2)%3] (last read iter t-1) is safe to overwrite.
template <typename TC>
__global__ __launch_bounds__(256) void mfma_gemm(const bf16* __restrict__ A,
                                                 const bf16* __restrict__ BT,
                                                 TC* __restrict__ C,
                                                 int M, int N, int K) {
    __shared__ short As[3][128 * 32];
    __shared__ short Bs[3][128 * 32];
    const int tid = threadIdx.x;
    const int w = tid >> 6, lane = tid & 63;
    const int col16 = lane & 15, quad = lane >> 4;
    const int row0 = blockIdx.y * 128, col0 = blockIdx.x * 128;
    const int wr0 = (w >> 1) * 64, wc0 = (w & 1) * 64;
    const int nt = K / 32;

    auto issue = [&](int t, int b) {
        const int k0 = t * 32;
        #pragma unroll
        for (int it = 0; it < 2; it++) {
            int cc = w * 128 + it * 64 + lane;
            int r = cc >> 2, seg = cc & 3;
            const bf16* g = A + (size_t)(row0 + r) * K + k0 + ((seg ^ (r & 3)) * 8);
            __builtin_amdgcn_global_load_lds(
                (const __attribute__((address_space(1))) unsigned int*)g,
                (__attribute__((address_space(3))) unsigned int*)&As[b][(w * 128 + it * 64) * 8],
                16, 0, 0);
        }
        #pragma unroll
        for (int it = 0; it < 2; it++) {
            int cc = w * 128 + it * 64 + lane;
            int r = cc >> 2, seg = cc & 3;
            const bf16* g = BT + (size_t)(col0 + r) * K + k0 + ((seg ^ (r & 3)) * 8);
            __builtin_amdgcn_global_load_lds(
                (const __attribute__((address_space(1))) unsigned int*)g,
                (__attribute__((address_space(3))) unsigned int*)&Bs[b][(w * 128 + it * 64) * 8],
                16, 0, 0);
        }
    };

    floatx4 acc[4][4];
    #pragma unroll
    for (int mi = 0; mi < 4; mi++)
        #pragma unroll
        for (int ni = 0; ni < 4; ni++) acc[mi][ni] = (floatx4){0.f, 0.f, 0.f, 0.f};

    issue(0, 0);
    if (1 < nt) issue(1, 1);

    for (int t = 0; t < nt; ++t) {
        const int cb = t % 3;
        if (t + 1 < nt) { asm volatile("s_waitcnt vmcnt(4)" ::: "memory"); }
        else            { asm volatile("s_waitcnt vmcnt(0)" ::: "memory"); }
        __builtin_amdgcn_sched_barrier(0);
        __builtin_amdgcn_s_barrier();
        __builtin_amdgcn_sched_barrier(0);
        if (t + 2 < nt) issue(t + 2, (t + 2) % 3);

        short8 af[4], bfr[4];
        #pragma unroll
        for (int mi = 0; mi < 4; mi++) {
            int r = wr0 + mi * 16 + col16;
            af[mi] = *(const short8*)&As[cb][r * 32 + ((quad ^ (r & 3)) * 8)];
        }
        #pragma unroll
        for (int ni = 0; ni < 4; ni++) {
            int r = wc0 + ni * 16 + col16;
            bfr[ni] = *(const short8*)&Bs[cb][r * 32 + ((quad ^ (r & 3)) * 8)];
        }
        __builtin_amdgcn_s_setprio(1);
        #pragma unroll
        for (int mi = 0; mi < 4; mi++)
            #pragma unroll
            for (int ni = 0; ni < 4; ni++)
                acc[mi][ni] = __builtin_amdgcn_mfma_f32_16x16x32_bf16(af[mi], bfr[ni], acc[mi][ni], 0, 0, 0);
        __builtin_amdgcn_s_setprio(0);
    }
    #pragma unroll
    for (int mi = 0; mi < 4; mi++)
        #pragma unroll
        for (int ni = 0; ni < 4; ni++)
            #pragma unroll
            for (int r = 0; r < 4; r++)
                store_c(&C[(size_t)(row0 + wr0 + mi * 16 + quad * 4 + r) * N +
                           col0 + wc0 + ni * 16 + col16],
                        acc[mi][ni][r]);
}

// ---------------- RoPE (interleaved pairs) on packed qkv — q and k in one launch
__global__ void rope_all(bf16* __restrict__ qkv, const float* __restrict__ cs,
                         const float* __restrict__ sn, int totq, int total) {
    int idx = blockIdx.x * blockDim.x + threadIdx.x;
    if (idx >= total) return;
    bf16* base; int n_heads; int rel;
    if (idx < totq) { base = qkv;        n_heads = NH;  rel = idx; }
    else            { base = qkv + 2048; n_heads = NKV; rel = idx - totq; }
    int i = rel & 63;
    int h = (rel >> 6) % n_heads;
    size_t bs = (size_t)rel / (64 * n_heads);
    int s = (int)(bs % SS);
    float c = cs[s * 64 + i];
    float si = sn[s * 64 + i];
    bf16* p = base + bs * QS + h * DH + 2 * i;
    float xr = __bfloat162float(p[0]), xi = __bfloat162float(p[1]);
    p[0] = f2b(xr * c - xi * si);
    p[1] = f2b(xr * si + xi * c);
}

// ---------------- V transpose: qkv packed v -> vt[b][kvh][d][s]
__global__ __launch_bounds__(256) void transpose_v(const bf16* __restrict__ qkv,
                                                   bf16* __restrict__ vt) {
    const int s0 = blockIdx.x * 64, d0 = blockIdx.y * 64;
    const int b = blockIdx.z >> 2, kvh = blockIdx.z & 3;
    __shared__ bf16 tile[64][65];
    const int tid = threadIdx.x;
    for (int i = tid; i < 4096; i += 256) {
        int r = i >> 6, c = i & 63;
        tile[r][c] = qkv[(size_t)(b * SS + s0 + r) * QS + 2560 + kvh * DH + d0 + c];
    }
    __syncthreads();
    for (int i = tid; i < 4096; i += 256) {
        int r = i >> 6, c = i & 63;
        vt[((size_t)(b * NKV + kvh) * DH + d0 + r) * SS + s0 + c] = tile[c][r];
    }
}

// ---------------- Flash attention (causal, GQA), bf16 MFMA 16x16x32
// Frozen round-3 structure (91.8 us): K/V double-buffered via global_load_lds
// w=16, one barrier/tile, both-sides XOR swizzle; softmax with MFMA ones-
// column row-sum, exp2 with folded scale, uniform causal branch, defer-rescale.
#define PPAD 72

__global__ __launch_bounds__(256) void flash_attn(const bf16* __restrict__ qkv,
                                                  const bf16* __restrict__ vt,
                                                  bf16* __restrict__ ao) {
    const int bx = blockIdx.x, h = blockIdx.y, b = blockIdx.z;
    const int kvh = h >> 2;
    __shared__ short Ks[2][64 * 128];   // [kvrow][d-seg], swizzled segs
    __shared__ short Vs[2][128 * 64];   // [d-row][s-seg], swizzled segs
    __shared__ short Ps[4 * 16 * PPAD];
    const int tid = threadIdx.x;
    const int w = tid >> 6, lane = tid & 63;
    const int col = lane & 15, quad = lane >> 4;
    const int c7 = col & 7;
    const float C = 0.12751746517859245f;  // (1/sqrt(128)) * log2(e)

    const int krl = lane >> 4, kseg = lane & 15;   // K: 4 rows / inst
    const int vrl = lane >> 3, vseg = lane & 7;    // V: 8 rows / inst

    const bf16* kgb = qkv + (size_t)b * SS * QS + 2048 + kvh * DH;
    const bf16* vgb = vt + (size_t)(b * NKV + kvh) * DH * SS;

    const short8 vone = {0x3F80, 0x3F80, 0x3F80, 0x3F80, 0x3F80, 0x3F80, 0x3F80, 0x3F80};

    for (int phase = 0; phase < 2; phase++) {
        const int qt = phase == 0 ? bx : (SS / 64 - 1 - bx);
        const int q0 = qt * 64;

        short8 aq[4];
        const bf16* qbase = qkv + (size_t)(b * SS + q0 + w * 16 + col) * QS + h * DH;
        #pragma unroll
        for (int kc = 0; kc < 4; kc++)
            aq[kc] = *(const short8*)(qbase + kc * 32 + quad * 8);

        floatx4 o[8];
        #pragma unroll
        for (int dt = 0; dt < 8; dt++) o[dt] = (floatx4){0.f, 0.f, 0.f, 0.f};
        floatx4 oL = (floatx4){0.f, 0.f, 0.f, 0.f};
        float mrow[4] = {-3e38f, -3e38f, -3e38f, -3e38f};

        for (int kt = 0; kt <= qt; kt++) {
            const int cur = kt & 1;
            __syncthreads();
            if (kt == 0) {
                #pragma unroll
                for (int it = 0; it < 4; it++) {
                    int row = w * 16 + it * 4 + krl;
                    const bf16* g = kgb + (size_t)row * QS + ((kseg ^ (row & 7)) * 8);
                    __builtin_amdgcn_global_load_lds(
                        (const __attribute__((address_space(1))) unsigned int*)g,
                        (__attribute__((address_space(3))) unsigned int*)&Ks[0][(w * 16 + it * 4) * 128],
                        16, 0, 0);
                }
                #pragma unroll
                for (int it = 0; it < 4; it++) {
                    int drow = w * 32 + it * 8 + vrl;
                    const bf16* g = vgb + (size_t)drow * SS + ((vseg ^ (drow & 7)) * 8);
                    __builtin_amdgcn_global_load_lds(
                        (const __attribute__((address_space(1))) unsigned int*)g,
                        (__attribute__((address_space(3))) unsigned int*)&Vs[0][(w * 32 + it * 8) * 64],
                        16, 0, 0);
                }
                __syncthreads();
            }
            if (kt < qt) {
                const int nk0 = (kt + 1) * 64;
                #pragma unroll
                for (int it = 0; it < 4; it++) {
                    int row = w * 16 + it * 4 + krl;
                    const bf16* g = kgb + (size_t)(nk0 + row) * QS + ((kseg ^ (row & 7)) * 8);
                    __builtin_amdgcn_global_load_lds(
                        (const __attribute__((address_space(1))) unsigned int*)g,
                        (__attribute__((address_space(3))) unsigned int*)&Ks[cur ^ 1][(w * 16 + it * 4) * 128],
                        16, 0, 0);
                }
                #pragma unroll
                for (int it = 0; it < 4; it++) {
                    int drow = w * 32 + it * 8 + vrl;
                    const bf16* g = vgb + (size_t)drow * SS + nk0 + ((vseg ^ (drow & 7)) * 8);
                    __builtin_amdgcn_global_load_lds(
                        (const __attribute__((address_space(1))) unsigned int*)g,
                        (__attribute__((address_space(3))) unsigned int*)&Vs[cur ^ 1][(w * 32 + it * 8) * 64],
                        16, 0, 0);
                }
            }

            const int k0 = kt * 64;
            floatx4 s[4];
            __builtin_amdgcn_s_setprio(1);
            #pragma unroll
            for (int n = 0; n < 4; n++) {
                s[n] = (floatx4){0.f, 0.f, 0.f, 0.f};
                #pragma unroll
                for (int kc = 0; kc < 4; kc++) {
                    short8 bk = *(const short8*)&Ks[cur][(n * 16 + col) * 128 + (((kc * 4 + quad) ^ c7) * 8)];
                    s[n] = __builtin_amdgcn_mfma_f32_16x16x32_bf16(aq[kc], bk, s[n], 0, 0, 0);
                }
            }
            __builtin_amdgcn_s_setprio(0);

            if (kt == qt) {
                #pragma unroll
                for (int n = 0; n < 4; n++)
                    #pragma unroll
                    for (int r = 0; r < 4; r++)
                        if ((k0 + n * 16 + col) > (q0 + w * 16 + quad * 4 + r)) s[n][r] = -3e38f;
            }

            float rmx[4];
            #pragma unroll
            for (int r = 0; r < 4; r++) {
                float rm = fmaxf(fmaxf(s[0][r], s[1][r]), fmaxf(s[2][r], s[3][r]));
                rm = fmaxf(rm, __shfl_xor(rm, 1));
                rm = fmaxf(rm, __shfl_xor(rm, 2));
                rm = fmaxf(rm, __shfl_xor(rm, 4));
                rm = fmaxf(rm, __shfl_xor(rm, 8));
                rmx[r] = fmaxf(rm, mrow[r]);
            }
            bool grow = (rmx[0] > mrow[0]) | (rmx[1] > mrow[1]) |
                        (rmx[2] > mrow[2]) | (rmx[3] > mrow[3]);
            if (__any((int)grow)) {
                float al[4];
                #pragma unroll
                for (int r = 0; r < 4; r++) {
                    al[r] = EX2((mrow[r] - rmx[r]) * C);
                    mrow[r] = rmx[r];
                }
                #pragma unroll
                for (int dt = 0; dt < 8; dt++)
                    #pragma unroll
                    for (int r = 0; r < 4; r++) o[dt][r] *= al[r];
                #pragma unroll
                for (int r = 0; r < 4; r++) oL[r] *= al[r];
            }
            float mC[4];
            #pragma unroll
            for (int r = 0; r < 4; r++) mC[r] = mrow[r] * C;

            short* pw = &Ps[w * 16 * PPAD];
            #pragma unroll
            for (int n = 0; n < 4; n++)
                #pragma unroll
                for (int r = 0; r < 4; r++)
                    pw[(quad * 4 + r) * PPAD + n * 16 + col] =
                        f2bs(EX2(__builtin_fmaf(s[n][r], C, -mC[r])));

            short8 ap0 = *(const short8*)&pw[col * PPAD + quad * 8];
            short8 ap1 = *(const short8*)&pw[col * PPAD + 32 + quad * 8];
            __builtin_amdgcn_s_setprio(1);
            #pragma unroll
            for (int dt = 0; dt < 8; dt++) {
                short8 bv0 = *(const short8*)&Vs[cur][(dt * 16 + col) * 64 + ((quad ^ c7) * 8)];
                o[dt] = __builtin_amdgcn_mfma_f32_16x16x32_bf16(ap0, bv0, o[dt], 0, 0, 0);
                short8 bv1 = *(const short8*)&Vs[cur][(dt * 16 + col) * 64 + (((quad + 4) ^ c7) * 8)];
                o[dt] = __builtin_amdgcn_mfma_f32_16x16x32_bf16(ap1, bv1, o[dt], 0, 0, 0);
            }
            oL = __builtin_amdgcn_mfma_f32_16x16x32_bf16(ap0, vone, oL, 0, 0, 0);
            oL = __builtin_amdgcn_mfma_f32_16x16x32_bf16(ap1, vone, oL, 0, 0, 0);
            __builtin_amdgcn_s_setprio(0);
        }
        #pragma unroll
        for (int r = 0; r < 4; r++) {
            float inv = 1.f / oL[r];
            int srow = q0 + w * 16 + quad * 4 + r;
            bf16* op = ao + ((size_t)(b * SS + srow) * NH + h) * DH;
            #pragma unroll
            for (int dt = 0; dt < 8; dt++)
                op[dt * 16 + col] = f2b(o[dt][r] * inv);
        }
    }
}

extern "C" void kernel_launch(void* const* d_in, const int* in_sizes, int n_in,
                              void* d_out, int out_size, void* d_ws, size_t ws_size,
                              hipStream_t stream) {
    const float* x  = (const float*)d_in[0];
    const float* fc = (const float*)d_in[1];
    const float* fs = (const float*)d_in[2];
    // d_in[3] = mask: exactly causal -> implemented directly
    const float* wq = (const float*)d_in[4];
    const float* wk = (const float*)d_in[5];
    const float* wv = (const float*)d_in[6];
    const float* wo = (const float*)d_in[7];
    float* out = (float*)d_out;

    const int M = BB * SS;  // 4096
    bf16* qkv    = (bf16*)d_ws;               // [0, 12582912)
    bf16* xb     = qkv + (size_t)M * QS;      // [12582912, 20971520)
    bf16* wqkvT  = xb + (size_t)M * DM;       // [20971520, 27262976)
    bf16* ao     = xb;                        // alias: xb dead after qkv GEMM
    bf16* vt     = wqkvT;                     // alias: wqkvT dead after qkv GEMM
    bf16* woT    = qkv;                       // alias: qkv dead after flash

    dim3 blk(256);
    convert_x<<<(M * DM / 4 + 255) / 256, blk, 0, stream>>>((const float4*)x, xb, M * DM / 4);
    convert_wqkv<<<dim3(QS / 64, DM / 64), blk, 0, stream>>>(wq, wk, wv, wqkvT);

    mfma_gemm<bf16><<<dim3(QS / 128, M / 128), blk, 0, stream>>>(xb, wqkvT, qkv, M, QS, DM);

    const int totq = BB * SS * NH * 64;
    const int totk = BB * SS * NKV * 64;
    rope_all<<<(totq + totk + 255) / 256, blk, 0, stream>>>(qkv, fc, fs, totq, totq + totk);

    transpose_v<<<dim3(SS / 64, DH / 64, BB * NKV), blk, 0, stream>>>(qkv, vt);

    flash_attn<<<dim3(SS / 128, NH, BB), blk, 0, stream>>>(qkv, vt, ao);

    convert_wT<<<dim3(DM / 64, DM / 64), blk, 0, stream>>>(wo, woT, DM, DM);
    mfma_gemm<float><<<dim3(DM / 128, M / 128), blk, 0, stream>>>(ao, woT, out, M, DM, DM);
}

// Round 5
// 341.568 us; speedup vs baseline: 1.5422x; 1.0114x over previous
//
#include <hip/hip_runtime.h>
#include <hip/hip_bf16.h>

#define BB 2
#define SS 2048
#define DM 2048
#define NH 16
#define NKV 4
#define DH 128
#define QS 3072   // packed qkv row stride: 2048 q | 512 k | 512 v

typedef __hip_bfloat16 bf16;
typedef short short8 __attribute__((ext_vector_type(8)));
typedef float floatx4 __attribute__((ext_vector_type(4)));

#if __has_builtin(__builtin_amdgcn_exp2f)
#define EX2(x) __builtin_amdgcn_exp2f(x)
#else
#define EX2(x) exp2f(x)
#endif

__device__ __forceinline__ bf16 f2b(float v) { return __float2bfloat16(v); }
__device__ __forceinline__ short f2bs(float v) {
    bf16 t = __float2bfloat16(v);
    return __builtin_bit_cast(short, t);
}
__device__ __forceinline__ void store_c(bf16* p, float v) { *p = __float2bfloat16(v); }
__device__ __forceinline__ void store_c(float* p, float v) { *p = v; }

// ---------------- x fp32 -> bf16 (vectorized)
__global__ __launch_bounds__(256) void convert_x(const float4* __restrict__ x,
                                                 bf16* __restrict__ xb, int n4) {
    int i = blockIdx.x * blockDim.x + threadIdx.x;
    if (i >= n4) return;
    float4 v = x[i];
    bf16* p = xb + (size_t)i * 4;
    p[0] = f2b(v.x); p[1] = f2b(v.y); p[2] = f2b(v.z); p[3] = f2b(v.w);
}

// ---------------- weight fp32 [Kd][N] -> bf16 transposed [N][Kd] (wo path)
__global__ __launch_bounds__(256) void convert_wT(const float* __restrict__ w,
                                                  bf16* __restrict__ outT,
                                                  int N, int Kd) {
    const int n0 = blockIdx.x * 64, k0 = blockIdx.y * 64;
    __shared__ float tile[64][65];
    const int tid = threadIdx.x;
    for (int i = tid; i < 4096; i += 256) {
        int r = i >> 6, c = i & 63;  // r: k-local, c: n-local
        tile[r][c] = w[(size_t)(k0 + r) * N + n0 + c];
    }
    __syncthreads();
    for (int i = tid; i < 4096; i += 256) {
        int r = i >> 6, c = i & 63;  // r: n-local, c: k-local
        outT[(size_t)(n0 + r) * Kd + k0 + c] = f2b(tile[c][r]);
    }
}

// ---------------- fused wq|wk|wv fp32 -> bf16 transposed into wqkvT[3072][2048]
__global__ __launch_bounds__(256) void convert_wqkv(const float* __restrict__ wq,
                                                    const float* __restrict__ wk,
                                                    const float* __restrict__ wv,
                                                    bf16* __restrict__ outT) {
    const int bx = blockIdx.x;            // 48 col-tiles of the packed output
    const float* w; int N; int n0;
    if (bx < 32)      { w = wq; N = 2048; n0 = bx * 64; }
    else if (bx < 40) { w = wk; N = 512;  n0 = (bx - 32) * 64; }
    else              { w = wv; N = 512;  n0 = (bx - 40) * 64; }
    const int k0 = blockIdx.y * 64;
    const int gn0 = bx * 64;              // row in packed outT
    __shared__ float tile[64][65];
    const int tid = threadIdx.x;
    for (int i = tid; i < 4096; i += 256) {
        int r = i >> 6, c = i & 63;
        tile[r][c] = w[(size_t)(k0 + r) * N + n0 + c];
    }
    __syncthreads();
    for (int i = tid; i < 4096; i += 256) {
        int r = i >> 6, c = i & 63;
        outT[(size_t)(gn0 + r) * DM + k0 + c] = f2b(tile[c][r]);
    }
}

// ---------------- MFMA GEMM: C[M,N] = A[M,K] @ BT[N,K]^T, bf16 in, fp32 acc
// Round-4 schedule (T4 counted-vmcnt, 2-deep prefetch, triple buffer) +
// Round-5: bijective XCD-aware block swizzle (T1): consecutive dispatch ids
// round-robin the 8 XCDs; remap so each XCD owns a contiguous chunk of
// tile-rows -> A-panels become L2-resident per XCD. Requires nwg%8==0
// (gemm1: 768, gemm2: 512 -- both OK).
template <typename TC>
__global__ __launch_bounds__(256) void mfma_gemm(const bf16* __restrict__ A,
                                                 const bf16* __restrict__ BT,
                                                 TC* __restrict__ C,
                                                 int M, int N, int K) {
    __shared__ short As[3][128 * 32];
    __shared__ short Bs[3][128 * 32];
    const int tid = threadIdx.x;
    const int w = tid >> 6, lane = tid & 63;
    const int col16 = lane & 15, quad = lane >> 4;
    // XCD swizzle
    const int gx = gridDim.x;
    const int nwg = gx * gridDim.y;
    int lin = blockIdx.y * gx + blockIdx.x;
    lin = (lin & 7) * (nwg >> 3) + (lin >> 3);
    const int row0 = (lin / gx) * 128, col0 = (lin % gx) * 128;
    const int wr0 = (w >> 1) * 64, wc0 = (w & 1) * 64;
    const int nt = K / 32;

    auto issue = [&](int t, int b) {
        const int k0 = t * 32;
        #pragma unroll
        for (int it = 0; it < 2; it++) {
            int cc = w * 128 + it * 64 + lane;
            int r = cc >> 2, seg = cc & 3;
            const bf16* g = A + (size_t)(row0 + r) * K + k0 + ((seg ^ (r & 3)) * 8);
            __builtin_amdgcn_global_load_lds(
                (const __attribute__((address_space(1))) unsigned int*)g,
                (__attribute__((address_space(3))) unsigned int*)&As[b][(w * 128 + it * 64) * 8],
                16, 0, 0);
        }
        #pragma unroll
        for (int it = 0; it < 2; it++) {
            int cc = w * 128 + it * 64 + lane;
            int r = cc >> 2, seg = cc & 3;
            const bf16* g = BT + (size_t)(col0 + r) * K + k0 + ((seg ^ (r & 3)) * 8);
            __builtin_amdgcn_global_load_lds(
                (const __attribute__((address_space(1))) unsigned int*)g,
                (__attribute__((address_space(3))) unsigned int*)&Bs[b][(w * 128 + it * 64) * 8],
                16, 0, 0);
        }
    };

    floatx4 acc[4][4];
    #pragma unroll
    for (int mi = 0; mi < 4; mi++)
        #pragma unroll
        for (int ni = 0; ni < 4; ni++) acc[mi][ni] = (floatx4){0.f, 0.f, 0.f, 0.f};

    issue(0, 0);
    if (1 < nt) issue(1, 1);

    for (int t = 0; t < nt; ++t) {
        const int cb = t % 3;
        if (t + 1 < nt) { asm volatile("s_waitcnt vmcnt(4)" ::: "memory"); }
        else            { asm volatile("s_waitcnt vmcnt(0)" ::: "memory"); }
        __builtin_amdgcn_sched_barrier(0);
        __builtin_amdgcn_s_barrier();
        __builtin_amdgcn_sched_barrier(0);
        if (t + 2 < nt) issue(t + 2, (t + 2) % 3);

        short8 af[4], bfr[4];
        #pragma unroll
        for (int mi = 0; mi < 4; mi++) {
            int r = wr0 + mi * 16 + col16;
            af[mi] = *(const short8*)&As[cb][r * 32 + ((quad ^ (r & 3)) * 8)];
        }
        #pragma unroll
        for (int ni = 0; ni < 4; ni++) {
            int r = wc0 + ni * 16 + col16;
            bfr[ni] = *(const short8*)&Bs[cb][r * 32 + ((quad ^ (r & 3)) * 8)];
        }
        __builtin_amdgcn_s_setprio(1);
        #pragma unroll
        for (int mi = 0; mi < 4; mi++)
            #pragma unroll
            for (int ni = 0; ni < 4; ni++)
                acc[mi][ni] = __builtin_amdgcn_mfma_f32_16x16x32_bf16(af[mi], bfr[ni], acc[mi][ni], 0, 0, 0);
        __builtin_amdgcn_s_setprio(0);
    }
    #pragma unroll
    for (int mi = 0; mi < 4; mi++)
        #pragma unroll
        for (int ni = 0; ni < 4; ni++)
            #pragma unroll
            for (int r = 0; r < 4; r++)
                store_c(&C[(size_t)(row0 + wr0 + mi * 16 + quad * 4 + r) * N +
                           col0 + wc0 + ni * 16 + col16],
                        acc[mi][ni][r]);
}

// ---------------- RoPE (interleaved pairs) on packed qkv — q and k in one launch
__global__ void rope_all(bf16* __restrict__ qkv, const float* __restrict__ cs,
                         const float* __restrict__ sn, int totq, int total) {
    int idx = blockIdx.x * blockDim.x + threadIdx.x;
    if (idx >= total) return;
    bf16* base; int n_heads; int rel;
    if (idx < totq) { base = qkv;        n_heads = NH;  rel = idx; }
    else            { base = qkv + 2048; n_heads = NKV; rel = idx - totq; }
    int i = rel & 63;
    int h = (rel >> 6) % n_heads;
    size_t bs = (size_t)rel / (64 * n_heads);
    int s = (int)(bs % SS);
    float c = cs[s * 64 + i];
    float si = sn[s * 64 + i];
    bf16* p = base + bs * QS + h * DH + 2 * i;
    float xr = __bfloat162float(p[0]), xi = __bfloat162float(p[1]);
    p[0] = f2b(xr * c - xi * si);
    p[1] = f2b(xr * si + xi * c);
}

// ---------------- V transpose: qkv packed v -> vt[b][kvh][d][s]
__global__ __launch_bounds__(256) void transpose_v(const bf16* __restrict__ qkv,
                                                   bf16* __restrict__ vt) {
    const int s0 = blockIdx.x * 64, d0 = blockIdx.y * 64;
    const int b = blockIdx.z >> 2, kvh = blockIdx.z & 3;
    __shared__ bf16 tile[64][65];
    const int tid = threadIdx.x;
    for (int i = tid; i < 4096; i += 256) {
        int r = i >> 6, c = i & 63;
        tile[r][c] = qkv[(size_t)(b * SS + s0 + r) * QS + 2560 + kvh * DH + d0 + c];
    }
    __syncthreads();
    for (int i = tid; i < 4096; i += 256) {
        int r = i >> 6, c = i & 63;
        vt[((size_t)(b * NKV + kvh) * DH + d0 + r) * SS + s0 + c] = tile[c][r];
    }
}

// ---------------- Flash attention (causal, GQA), bf16 MFMA 16x16x32
// Frozen round-3 structure; round-5 deltas:
//   * PPAD 72 -> 88: Ps b16-write banks = (16q + 12r + 8n + col/2)%32 ->
//     only 2-way (free, m136) vs 4-way at 72; b128 read start-groups
//     (3*col+quad)%8 stay uniform (conflict-free); rows stay 16B-aligned.
//   * defer-rescale THR = 90.5 raw units (= 8 nats; P <= e^8, exact
//     cancellation in o/oL; bf16-safe). T13, measured +5% on attn.
#define PPAD 88

__global__ __launch_bounds__(256) void flash_attn(const bf16* __restrict__ qkv,
                                                  const bf16* __restrict__ vt,
                                                  bf16* __restrict__ ao) {
    const int bx = blockIdx.x, h = blockIdx.y, b = blockIdx.z;
    const int kvh = h >> 2;
    __shared__ short Ks[2][64 * 128];   // [kvrow][d-seg], swizzled segs
    __shared__ short Vs[2][128 * 64];   // [d-row][s-seg], swizzled segs
    __shared__ short Ps[4 * 16 * PPAD];
    const int tid = threadIdx.x;
    const int w = tid >> 6, lane = tid & 63;
    const int col = lane & 15, quad = lane >> 4;
    const int c7 = col & 7;
    const float C = 0.12751746517859245f;  // (1/sqrt(128)) * log2(e)
    const float THR_RAW = 90.5f;           // 8 nats in raw-score units

    const int krl = lane >> 4, kseg = lane & 15;   // K: 4 rows / inst
    const int vrl = lane >> 3, vseg = lane & 7;    // V: 8 rows / inst

    const bf16* kgb = qkv + (size_t)b * SS * QS + 2048 + kvh * DH;
    const bf16* vgb = vt + (size_t)(b * NKV + kvh) * DH * SS;

    const short8 vone = {0x3F80, 0x3F80, 0x3F80, 0x3F80, 0x3F80, 0x3F80, 0x3F80, 0x3F80};

    for (int phase = 0; phase < 2; phase++) {
        const int qt = phase == 0 ? bx : (SS / 64 - 1 - bx);
        const int q0 = qt * 64;

        short8 aq[4];
        const bf16* qbase = qkv + (size_t)(b * SS + q0 + w * 16 + col) * QS + h * DH;
        #pragma unroll
        for (int kc = 0; kc < 4; kc++)
            aq[kc] = *(const short8*)(qbase + kc * 32 + quad * 8);

        floatx4 o[8];
        #pragma unroll
        for (int dt = 0; dt < 8; dt++) o[dt] = (floatx4){0.f, 0.f, 0.f, 0.f};
        floatx4 oL = (floatx4){0.f, 0.f, 0.f, 0.f};
        float mrow[4] = {-3e38f, -3e38f, -3e38f, -3e38f};

        for (int kt = 0; kt <= qt; kt++) {
            const int cur = kt & 1;
            __syncthreads();
            if (kt == 0) {
                #pragma unroll
                for (int it = 0; it < 4; it++) {
                    int row = w * 16 + it * 4 + krl;
                    const bf16* g = kgb + (size_t)row * QS + ((kseg ^ (row & 7)) * 8);
                    __builtin_amdgcn_global_load_lds(
                        (const __attribute__((address_space(1))) unsigned int*)g,
                        (__attribute__((address_space(3))) unsigned int*)&Ks[0][(w * 16 + it * 4) * 128],
                        16, 0, 0);
                }
                #pragma unroll
                for (int it = 0; it < 4; it++) {
                    int drow = w * 32 + it * 8 + vrl;
                    const bf16* g = vgb + (size_t)drow * SS + ((vseg ^ (drow & 7)) * 8);
                    __builtin_amdgcn_global_load_lds(
                        (const __attribute__((address_space(1))) unsigned int*)g,
                        (__attribute__((address_space(3))) unsigned int*)&Vs[0][(w * 32 + it * 8) * 64],
                        16, 0, 0);
                }
                __syncthreads();
            }
            if (kt < qt) {
                const int nk0 = (kt + 1) * 64;
                #pragma unroll
                for (int it = 0; it < 4; it++) {
                    int row = w * 16 + it * 4 + krl;
                    const bf16* g = kgb + (size_t)(nk0 + row) * QS + ((kseg ^ (row & 7)) * 8);
                    __builtin_amdgcn_global_load_lds(
                        (const __attribute__((address_space(1))) unsigned int*)g,
                        (__attribute__((address_space(3))) unsigned int*)&Ks[cur ^ 1][(w * 16 + it * 4) * 128],
                        16, 0, 0);
                }
                #pragma unroll
                for (int it = 0; it < 4; it++) {
                    int drow = w * 32 + it * 8 + vrl;
                    const bf16* g = vgb + (size_t)drow * SS + nk0 + ((vseg ^ (drow & 7)) * 8);
                    __builtin_amdgcn_global_load_lds(
                        (const __attribute__((address_space(1))) unsigned int*)g,
                        (__attribute__((address_space(3))) unsigned int*)&Vs[cur ^ 1][(w * 32 + it * 8) * 64],
                        16, 0, 0);
                }
            }

            const int k0 = kt * 64;
            floatx4 s[4];
            __builtin_amdgcn_s_setprio(1);
            #pragma unroll
            for (int n = 0; n < 4; n++) {
                s[n] = (floatx4){0.f, 0.f, 0.f, 0.f};
                #pragma unroll
                for (int kc = 0; kc < 4; kc++) {
                    short8 bk = *(const short8*)&Ks[cur][(n * 16 + col) * 128 + (((kc * 4 + quad) ^ c7) * 8)];
                    s[n] = __builtin_amdgcn_mfma_f32_16x16x32_bf16(aq[kc], bk, s[n], 0, 0, 0);
                }
            }
            __builtin_amdgcn_s_setprio(0);

            if (kt == qt) {
                #pragma unroll
                for (int n = 0; n < 4; n++)
                    #pragma unroll
                    for (int r = 0; r < 4; r++)
                        if ((k0 + n * 16 + col) > (q0 + w * 16 + quad * 4 + r)) s[n][r] = -3e38f;
            }

            float rmx[4];
            #pragma unroll
            for (int r = 0; r < 4; r++) {
                float rm = fmaxf(fmaxf(s[0][r], s[1][r]), fmaxf(s[2][r], s[3][r]));
                rm = fmaxf(rm, __shfl_xor(rm, 1));
                rm = fmaxf(rm, __shfl_xor(rm, 2));
                rm = fmaxf(rm, __shfl_xor(rm, 4));
                rm = fmaxf(rm, __shfl_xor(rm, 8));
                rmx[r] = fmaxf(rm, mrow[r]);
            }
            // defer-rescale (T13): only rescale when some row max grew by
            // more than THR_RAW; otherwise keep old mrow (P bounded by e^8).
            bool need = (rmx[0] - mrow[0] > THR_RAW) | (rmx[1] - mrow[1] > THR_RAW) |
                        (rmx[2] - mrow[2] > THR_RAW) | (rmx[3] - mrow[3] > THR_RAW);
            if (__any((int)need)) {
                float al[4];
                #pragma unroll
                for (int r = 0; r < 4; r++) {
                    al[r] = EX2((mrow[r] - rmx[r]) * C);
                    mrow[r] = rmx[r];
                }
                #pragma unroll
                for (int dt = 0; dt < 8; dt++)
                    #pragma unroll
                    for (int r = 0; r < 4; r++) o[dt][r] *= al[r];
                #pragma unroll
                for (int r = 0; r < 4; r++) oL[r] *= al[r];
            }
            float mC[4];
            #pragma unroll
            for (int r = 0; r < 4; r++) mC[r] = mrow[r] * C;

            short* pw = &Ps[w * 16 * PPAD];
            #pragma unroll
            for (int n = 0; n < 4; n++)
                #pragma unroll
                for (int r = 0; r < 4; r++)
                    pw[(quad * 4 + r) * PPAD + n * 16 + col] =
                        f2bs(EX2(__builtin_fmaf(s[n][r], C, -mC[r])));

            short8 ap0 = *(const short8*)&pw[col * PPAD + quad * 8];
            short8 ap1 = *(const short8*)&pw[col * PPAD + 32 + quad * 8];
            __builtin_amdgcn_s_setprio(1);
            #pragma unroll
            for (int dt = 0; dt < 8; dt++) {
                short8 bv0 = *(const short8*)&Vs[cur][(dt * 16 + col) * 64 + ((quad ^ c7) * 8)];
                o[dt] = __builtin_amdgcn_mfma_f32_16x16x32_bf16(ap0, bv0, o[dt], 0, 0, 0);
                short8 bv1 = *(const short8*)&Vs[cur][(dt * 16 + col) * 64 + (((quad + 4) ^ c7) * 8)];
                o[dt] = __builtin_amdgcn_mfma_f32_16x16x32_bf16(ap1, bv1, o[dt], 0, 0, 0);
            }
            oL = __builtin_amdgcn_mfma_f32_16x16x32_bf16(ap0, vone, oL, 0, 0, 0);
            oL = __builtin_amdgcn_mfma_f32_16x16x32_bf16(ap1, vone, oL, 0, 0, 0);
            __builtin_amdgcn_s_setprio(0);
        }
        #pragma unroll
        for (int r = 0; r < 4; r++) {
            float inv = 1.f / oL[r];
            int srow = q0 + w * 16 + quad * 4 + r;
            bf16* op = ao + ((size_t)(b * SS + srow) * NH + h) * DH;
            #pragma unroll
            for (int dt = 0; dt < 8; dt++)
                op[dt * 16 + col] = f2b(o[dt][r] * inv);
        }
    }
}

extern "C" void kernel_launch(void* const* d_in, const int* in_sizes, int n_in,
                              void* d_out, int out_size, void* d_ws, size_t ws_size,
                              hipStream_t stream) {
    const float* x  = (const float*)d_in[0];
    const float* fc = (const float*)d_in[1];
    const float* fs = (const float*)d_in[2];
    // d_in[3] = mask: exactly causal -> implemented directly
    const float* wq = (const float*)d_in[4];
    const float* wk = (const float*)d_in[5];
    const float* wv = (const float*)d_in[6];
    const float* wo = (const float*)d_in[7];
    float* out = (float*)d_out;

    const int M = BB * SS;  // 4096
    bf16* qkv    = (bf16*)d_ws;               // [0, 12582912)
    bf16* xb     = qkv + (size_t)M * QS;      // [12582912, 20971520)
    bf16* wqkvT  = xb + (size_t)M * DM;       // [20971520, 27262976)
    bf16* ao     = xb;                        // alias: xb dead after qkv GEMM
    bf16* vt     = wqkvT;                     // alias: wqkvT dead after qkv GEMM
    bf16* woT    = qkv;                       // alias: qkv dead after flash

    dim3 blk(256);
    convert_x<<<(M * DM / 4 + 255) / 256, blk, 0, stream>>>((const float4*)x, xb, M * DM / 4);
    convert_wqkv<<<dim3(QS / 64, DM / 64), blk, 0, stream>>>(wq, wk, wv, wqkvT);

    mfma_gemm<bf16><<<dim3(QS / 128, M / 128), blk, 0, stream>>>(xb, wqkvT, qkv, M, QS, DM);

    const int totq = BB * SS * NH * 64;
    const int totk = BB * SS * NKV * 64;
    rope_all<<<(totq + totk + 255) / 256, blk, 0, stream>>>(qkv, fc, fs, totq, totq + totk);

    transpose_v<<<dim3(SS / 64, DH / 64, BB * NKV), blk, 0, stream>>>(qkv, vt);

    flash_attn<<<dim3(SS / 128, NH, BB), blk, 0, stream>>>(qkv, vt, ao);

    convert_wT<<<dim3(DM / 64, DM / 64), blk, 0, stream>>>(wo, woT, DM, DM);
    mfma_gemm<float><<<dim3(DM / 128, M / 128), blk, 0, stream>>>(ao, woT, out, M, DM, DM);
}